// Round 14
// baseline (428.433 us; speedup 1.0000x reference)
//
#include <hip/hip_runtime.h>
#include <hip/hip_bf16.h>
#include <hip/hip_fp16.h>

#define FDIM 64
#define WPAD2 36  // transposed fp16-weight row stride in u32 (half2) units:
                  // 144 B, 16 B-aligned, stride mod 32 banks = 4 -> optimal
                  // 8-lane bank tiling for b128 reads (same as r13's WPAD=68)

// Bucketed CSR build parameters
#define NBLK_G 256        // chunk-grid for p1
#define CHUNK_CAP 8192    // max edges per chunk block (32 KB LDS stage)
#define BKT_SHIFT 7
#define BKT_NODES 128     // dest nodes per bucket
#define NB_MAX 512        // max buckets (N <= 65536)
#define STCAP 8192        // P4 LDS stage cap (edges)

__device__ __forceinline__ int clampi(int v, int n) { return min(max(v, 0), n - 1); }

// --------------------- convert fp32 -> fp16 shadow table (x4) ---------------
__global__ __launch_bounds__(256) void convert_half4(
    const float4* __restrict__ in4, __half2* __restrict__ out2, int n4)
{
    int i = blockIdx.x * 256 + threadIdx.x;
    if (i >= n4) return;
    float4 v = in4[i];
    out2[2 * i]     = __floats2half2_rn(v.x, v.y);
    out2[2 * i + 1] = __floats2half2_rn(v.z, v.w);
}

// ---- P1: block-local bin + contiguous stage + counts + starts table --------
__global__ __launch_bounds__(512) void p1_bin_stage(
    const int* __restrict__ rows, const int* __restrict__ cols,
    unsigned* __restrict__ pairs1, int* __restrict__ blockcnt,
    int* __restrict__ startsTbl, int n, int E, int nb, int chunk)
{
    __shared__ unsigned stage[CHUNK_CAP];
    __shared__ int hist[NB_MAX];
    __shared__ int curs[NB_MAX];
    int tid = threadIdx.x;
    int base = blockIdx.x * chunk;
    int cnt = E - base; if (cnt > chunk) cnt = chunk; if (cnt < 0) cnt = 0;
    for (int i = tid; i < NB_MAX; i += 512) hist[i] = 0;
    __syncthreads();
    for (int i = tid; i < cnt; i += 512)
        atomicAdd(&hist[clampi(cols[base + i], n) >> BKT_SHIFT], 1);
    __syncthreads();
    for (int b = tid; b < nb; b += 512) blockcnt[blockIdx.x * nb + b] = hist[b];
    __syncthreads();
    for (int off = 1; off < NB_MAX; off <<= 1) {
        int t = (tid >= off) ? hist[tid - off] : 0;
        __syncthreads();
        hist[tid] += t;
        __syncthreads();
    }
    curs[tid] = (tid == 0) ? 0 : hist[tid - 1];
    __syncthreads();
    // persist chunk-local exclusive starts BEFORE atomics mutate curs
    for (int b = tid; b < nb; b += 512) startsTbl[blockIdx.x * nb + b] = curs[b];
    __syncthreads();
    for (int i = tid; i < cnt; i += 512) {
        int c = clampi(cols[base + i], n);
        int r = clampi(rows[base + i], n);
        int p = atomicAdd(&curs[c >> BKT_SHIFT], 1);
        stage[p] = ((unsigned)r << 16) | (unsigned)c;
    }
    __syncthreads();
    for (int i = tid; i < cnt; i += 512) pairs1[base + i] = stage[i];
}

// --------------------- P2a: per-bucket column scan (1 wave / bucket) --------
__global__ __launch_bounds__(64) void p2a_colscan(
    int* __restrict__ blockcnt, int* __restrict__ bucketTot, int nb, int nblk)
{
    int b = blockIdx.x;
    int lane = threadIdx.x;
    int chunk = (nblk + 63) >> 6;
    int beg = lane * chunk;
    int endi = min(beg + chunk, nblk);
    int vals[8];
    int s = 0;
    for (int i = beg, j = 0; i < endi; ++i, ++j) {
        vals[j] = blockcnt[(size_t)i * nb + b];
        s += vals[j];
    }
    int incl = s;
#pragma unroll
    for (int o = 1; o < 64; o <<= 1) {
        int t = __shfl_up(incl, o, 64);
        if (lane >= o) incl += t;
    }
    int run = incl - s;
    for (int i = beg, j = 0; i < endi; ++i, ++j) {
        int t = vals[j];
        blockcnt[(size_t)i * nb + b] = run;
        run += t;
    }
    if (lane == 63) bucketTot[b] = incl;
}

// --------------------- P2b: bucket totals -> bucket bases -------------------
__global__ __launch_bounds__(512) void p2b_basescan(
    const int* __restrict__ bucketTot, int* __restrict__ bucketBase, int nb)
{
    __shared__ int tot[NB_MAX];
    int tid = threadIdx.x;
    tot[tid] = (tid < nb) ? bucketTot[tid] : 0;
    __syncthreads();
    for (int off = 1; off < NB_MAX; off <<= 1) {
        int t = (tid >= off) ? tot[tid - off] : 0;
        __syncthreads();
        tot[tid] += t;
        __syncthreads();
    }
    if (tid < nb) bucketBase[tid] = (tid == 0) ? 0 : tot[tid - 1];
    if (tid == 0) bucketBase[nb] = tot[nb - 1];
}

// ---- P4: per-bucket fine CSR, staging runs straight from pairs1 ------------
__global__ __launch_bounds__(256) void p4_fine2(
    const unsigned* __restrict__ pairs1, const int* __restrict__ blockcnt,
    const int* __restrict__ startsTbl, const int* __restrict__ bucketBase,
    int* __restrict__ rowptr, unsigned short* __restrict__ csridx,
    int n, int E, int nb, int chunk, int nblk)
{
    __shared__ unsigned st[STCAP];
    __shared__ int h[BKT_NODES];
    __shared__ int cur[BKT_NODES];
    int tid = threadIdx.x;
    int b = blockIdx.x;
    int beg = bucketBase[b], end = bucketBase[b + 1];
    int cnt = end - beg;
    for (int i = tid; i < BKT_NODES; i += 256) h[i] = 0;
    __syncthreads();
    bool fit = (cnt <= STCAP);     // block-uniform -> in-branch barriers legal
    if (fit) {
        for (int i = tid; i < nblk; i += 256) {
            int ccnt = E - i * chunk; if (ccnt > chunk) ccnt = chunk; if (ccnt < 0) ccnt = 0;
            int stt = startsTbl[(size_t)i * nb + b];
            int enn = (b + 1 < nb) ? startsTbl[(size_t)i * nb + b + 1] : ccnt;
            int dst = blockcnt[(size_t)i * nb + b];
            for (int j = stt; j < enn; ++j)
                st[dst + (j - stt)] = pairs1[(size_t)i * chunk + j];
        }
        __syncthreads();
        for (int i = tid; i < cnt; i += 256)
            atomicAdd(&h[st[i] & (BKT_NODES - 1)], 1);
    } else {
        for (int i = tid; i < nblk; i += 256) {
            int ccnt = E - i * chunk; if (ccnt > chunk) ccnt = chunk; if (ccnt < 0) ccnt = 0;
            int stt = startsTbl[(size_t)i * nb + b];
            int enn = (b + 1 < nb) ? startsTbl[(size_t)i * nb + b + 1] : ccnt;
            for (int j = stt; j < enn; ++j)
                atomicAdd(&h[pairs1[(size_t)i * chunk + j] & (BKT_NODES - 1)], 1);
        }
    }
    // barrier between histogram atomics and scan (round-9 race fix)
    __syncthreads();
    for (int off = 1; off < BKT_NODES; off <<= 1) {
        int t = (tid >= off && tid < BKT_NODES) ? h[tid - off] : 0;
        __syncthreads();
        if (tid < BKT_NODES) h[tid] += t;
        __syncthreads();
    }
    if (tid < BKT_NODES) {
        int node = b * BKT_NODES + tid;
        int startl = (tid == 0) ? 0 : h[tid - 1];
        cur[tid] = startl;
        if (node < n) rowptr[node] = beg + startl;
    }
    __syncthreads();
    if (fit) {
        for (int i = tid; i < cnt; i += 256) {
            unsigned pk = st[i];
            int p = atomicAdd(&cur[pk & (BKT_NODES - 1)], 1);
            csridx[beg + p] = (unsigned short)(pk >> 16);
        }
    } else {
        for (int i = tid; i < nblk; i += 256) {
            int ccnt = E - i * chunk; if (ccnt > chunk) ccnt = chunk; if (ccnt < 0) ccnt = 0;
            int stt = startsTbl[(size_t)i * nb + b];
            int enn = (b + 1 < nb) ? startsTbl[(size_t)i * nb + b + 1] : ccnt;
            for (int j = stt; j < enn; ++j) {
                unsigned pk = pairs1[(size_t)i * chunk + j];
                int p = atomicAdd(&cur[pk & (BKT_NODES - 1)], 1);
                csridx[beg + p] = (unsigned short)(pk >> 16);
            }
        }
    }
    if (b == nb - 1 && tid == 0) rowptr[n] = E;
}

// ------ Fused gather(mean, fp16 table) + dense ------------------------------
// r13 gather VERBATIM. Only change: Wt/Rt stored as fp16 half2 transposed
// (bank-optimal, r13-proven layout) -> LDS 37.4 KB -> ~21 KB, 4 -> 7
// blocks/CU, grid 1792 -> target ~28 resident waves/CU. Occupancy is the one
// knob not yet turned in isolation (r8/r10/r12 changed it together with VGPR
// or grid-side L2 behavior).
template <bool RELU, bool NORM, bool W16>
__global__ __launch_bounds__(256) void fused_sage_kernel(
    const int* __restrict__ rowptr, const unsigned short* __restrict__ csridx,
    const __half* __restrict__ src16, const float* __restrict__ src32,
    const float* __restrict__ W, const float* __restrict__ bvec,
    const float* __restrict__ R, float* __restrict__ out32,
    __half* __restrict__ out16, int n)
{
    __shared__ __align__(16) __half2 Wt2[FDIM][WPAD2];  // Wt2[j][k2]=(W[2k2][j],W[2k2+1][j])
    __shared__ __align__(16) __half2 Rt2[FDIM][WPAD2];
    __shared__ float bs[FDIM];
    __shared__ __align__(16) float aRow[4][FDIM];
    __shared__ __align__(16) float xRow[4][FDIM];
    int tid = threadIdx.x;
    for (int i = tid; i < FDIM * (FDIM / 2); i += 256) {
        int k2 = i >> 6, j = i & 63;
        Wt2[j][k2] = __floats2half2_rn(W[(2 * k2) * FDIM + j], W[(2 * k2 + 1) * FDIM + j]);
        Rt2[j][k2] = __floats2half2_rn(R[(2 * k2) * FDIM + j], R[(2 * k2 + 1) * FDIM + j]);
    }
    if (tid < FDIM) bs[tid] = bvec[tid];
    __syncthreads();

    int lane = tid & 63, w = tid >> 6;
    int g = lane >> 4;        // edge sub-group 0..3
    int q = lane & 15;        // 4-feature chunk within row

    for (int node = blockIdx.x * 4 + w; node < n; node += gridDim.x * 4) {
        int beg = rowptr[node], end = rowptr[node + 1];
        float4 s4 = make_float4(0.f, 0.f, 0.f, 0.f);
        for (int base = beg; base < end; base += 64) {
            int cnt = end - base; if (cnt > 64) cnt = 64;
            int ei = base + lane;
            int myidx = (ei < end) ? (int)csridx[ei] : 0;
            int steps = (cnt + 3) >> 2;
            for (int t = 0; t < steps; ++t) {
                int e = (t << 2) | g;
                int sidx = __shfl(myidx, e, 64);
                if (e < cnt) {
                    const float2* rp = (const float2*)(src16 + ((size_t)sidx << 6));
                    float2 vv = rp[q];                 // 4 halves = 8 B
                    __half2 ha = *reinterpret_cast<__half2*>(&vv.x);
                    __half2 hb = *reinterpret_cast<__half2*>(&vv.y);
                    float2 fa = __half22float2(ha);
                    float2 fb = __half22float2(hb);
                    s4.x += fa.x; s4.y += fa.y; s4.z += fb.x; s4.w += fb.y;
                }
            }
        }
#pragma unroll
        for (int o = 16; o < 64; o <<= 1) {
            s4.x += __shfl_xor(s4.x, o, 64);
            s4.y += __shfl_xor(s4.y, o, 64);
            s4.z += __shfl_xor(s4.z, o, 64);
            s4.w += __shfl_xor(s4.w, o, 64);
        }
        float dinv = 1.0f / fmaxf((float)(end - beg), 1.0f);
        if (g == 0) {
            aRow[w][q * 4 + 0] = s4.x * dinv;
            aRow[w][q * 4 + 1] = s4.y * dinv;
            aRow[w][q * 4 + 2] = s4.z * dinv;
            aRow[w][q * 4 + 3] = s4.w * dinv;
        }
        xRow[w][lane] = src32[((size_t)node << 6) + lane];
        // wave-local LDS RAW: ordered within the wave, no barrier needed
        float acc = bs[lane];
#pragma unroll
        for (int k8 = 0; k8 < FDIM / 8; ++k8) {
            // 8 k's per iter: 2 b128 weight reads (8 half2 each) +
            // 4 b128 broadcast reads of aRow/xRow
            float4 wv = *(const float4*)&Wt2[lane][k8 * 4];
            float4 rv = *(const float4*)&Rt2[lane][k8 * 4];
            float4 a0 = *(const float4*)&aRow[w][k8 * 8];
            float4 a1 = *(const float4*)&aRow[w][k8 * 8 + 4];
            float4 x0 = *(const float4*)&xRow[w][k8 * 8];
            float4 x1 = *(const float4*)&xRow[w][k8 * 8 + 4];
            const __half2* wh = (const __half2*)&wv;
            const __half2* rh = (const __half2*)&rv;
            float2 w0 = __half22float2(wh[0]), w1 = __half22float2(wh[1]);
            float2 w2 = __half22float2(wh[2]), w3 = __half22float2(wh[3]);
            float2 r0 = __half22float2(rh[0]), r1 = __half22float2(rh[1]);
            float2 r2 = __half22float2(rh[2]), r3 = __half22float2(rh[3]);
            acc = fmaf(a0.x, w0.x, acc); acc = fmaf(a0.y, w0.y, acc);
            acc = fmaf(a0.z, w1.x, acc); acc = fmaf(a0.w, w1.y, acc);
            acc = fmaf(a1.x, w2.x, acc); acc = fmaf(a1.y, w2.y, acc);
            acc = fmaf(a1.z, w3.x, acc); acc = fmaf(a1.w, w3.y, acc);
            acc = fmaf(x0.x, r0.x, acc); acc = fmaf(x0.y, r0.y, acc);
            acc = fmaf(x0.z, r1.x, acc); acc = fmaf(x0.w, r1.y, acc);
            acc = fmaf(x1.x, r2.x, acc); acc = fmaf(x1.y, r2.y, acc);
            acc = fmaf(x1.z, r3.x, acc); acc = fmaf(x1.w, r3.y, acc);
        }
        if (RELU) acc = fmaxf(acc, 0.0f);
        if (NORM) {
            float ss = acc * acc;
#pragma unroll
            for (int o = 32; o; o >>= 1) ss += __shfl_xor(ss, o, 64);
            acc *= 1.0f / fmaxf(sqrtf(ss), 1e-12f);
        }
        out32[((size_t)node << 6) + lane] = acc;
        if (W16) out16[((size_t)node << 6) + lane] = __float2half(acc);
    }
}

// ----------------- Atomic scatter path (fallback, 13.0 MB ws) ---------------
__global__ __launch_bounds__(256) void scatter_kernel(
    const float* __restrict__ src, const int* __restrict__ rows, const int* __restrict__ cols,
    float* __restrict__ agg, float* __restrict__ deg, int n, long long total)
{
    long long gid = (long long)blockIdx.x * 256 + threadIdx.x;
    if (gid >= total) return;
    int e = (int)(gid >> 6);
    int f = (int)(gid & 63);
    int r = clampi(rows[e], n), c = clampi(cols[e], n);
    atomicAdd(&agg[(long long)c * FDIM + f], src[(long long)r * FDIM + f]);
    if (f == 0) atomicAdd(&deg[c], 1.0f);
}

template <bool RELU, bool NORM>
__global__ __launch_bounds__(256) void dense_kernel(
    const float* __restrict__ agg, const float* __restrict__ deg, const float* __restrict__ x,
    const float* __restrict__ W, const float* __restrict__ b,
    const float* __restrict__ R, float* __restrict__ out, int n)
{
    __shared__ float Ws[FDIM][FDIM];
    __shared__ float Rs[FDIM][FDIM];
    __shared__ float bs[FDIM];
    __shared__ float aRow[4][FDIM];
    __shared__ float xRow[4][FDIM];
    int tid = threadIdx.x;
    for (int i = tid; i < FDIM * FDIM; i += 256) {
        Ws[i >> 6][i & 63] = W[i];
        Rs[i >> 6][i & 63] = R[i];
    }
    if (tid < FDIM) bs[tid] = b[tid];
    int j = tid & 63, r = tid >> 6;
    int row = blockIdx.x * 4 + r;
    if (row < n) {
        float d = fmaxf(deg[row], 1.0f);
        aRow[r][j] = agg[(long long)row * FDIM + j] / d;
        xRow[r][j] = x[(long long)row * FDIM + j];
    }
    __syncthreads();
    if (row >= n) return;
    float acc = bs[j];
#pragma unroll
    for (int k = 0; k < FDIM; ++k)
        acc = fmaf(aRow[r][k], Ws[k][j], fmaf(xRow[r][k], Rs[k][j], acc));
    if (RELU) acc = fmaxf(acc, 0.0f);
    if (NORM) {
        float ss = acc * acc;
#pragma unroll
        for (int o = 32; o; o >>= 1) ss += __shfl_xor(ss, o, 64);
        acc *= 1.0f / fmaxf(sqrtf(ss), 1e-12f);
    }
    out[(long long)row * FDIM + j] = acc;
}

// ---------------------------------------------------------------------------
extern "C" void kernel_launch(void* const* d_in, const int* in_sizes, int n_in,
                              void* d_out, int out_size, void* d_ws, size_t ws_size,
                              hipStream_t stream)
{
    const float* x  = (const float*)d_in[0];
    const int*   e0 = (const int*)d_in[1];
    const int*   e1 = (const int*)d_in[2];
    const float* W1 = (const float*)d_in[3];
    const float* b1 = (const float*)d_in[4];
    const float* R1 = (const float*)d_in[5];
    const float* W2 = (const float*)d_in[6];
    const float* b2 = (const float*)d_in[7];
    const float* R2 = (const float*)d_in[8];
    float* out = (float*)d_out;

    const int N = in_sizes[0] / FDIM;     // 50000
    const int E = in_sizes[1] / 2;        // 1600000

    const int nb = (N + BKT_NODES - 1) >> BKT_SHIFT;
    const int chunk = (E + NBLK_G - 1) / NBLK_G;
    const int FUSED_BLOCKS = 1792;        // 7 blocks/CU at ~21 KB LDS

    // Workspace (16-B aligned): pairs1[E] u32 | csridx[E] u16 |
    // blockcnt[NBLK_G*nb] | startsTbl[NBLK_G*nb] | bucketBase[nb+1] |
    // bucketTot[nb] | rowptr[N+1] | x16[N*64] half | h16[N*64] half  (~24.4 MB)
    auto align16 = [](size_t v) { return (v + 15) & ~(size_t)15; };
    size_t off = 0;
    size_t o_pairs1 = off; off = align16(off + (size_t)E * 4);
    size_t o_csr16  = off; off = align16(off + (size_t)E * 2);
    size_t o_bcnt   = off; off = align16(off + (size_t)NBLK_G * nb * 4);
    size_t o_stbl   = off; off = align16(off + (size_t)NBLK_G * nb * 4);
    size_t o_bbase  = off; off = align16(off + (size_t)(nb + 1) * 4);
    size_t o_btot   = off; off = align16(off + (size_t)nb * 4);
    size_t o_rowp   = off; off = align16(off + (size_t)(N + 1) * 4);
    size_t o_x16    = off; off = align16(off + (size_t)N * FDIM * 2);
    size_t o_h16    = off; off = align16(off + (size_t)N * FDIM * 2);
    const size_t need1 = off;

    const bool ok1 = (ws_size >= need1) && (N <= 65536) &&
                     (chunk <= CHUNK_CAP) && (nb <= NB_MAX) &&
                     ((N * FDIM & 3) == 0);

    if (ok1) {
        char* wsb = (char*)d_ws;
        unsigned*        pairs1     = (unsigned*)(wsb + o_pairs1);
        unsigned short*  csridx     = (unsigned short*)(wsb + o_csr16);
        int*             blockcnt   = (int*)(wsb + o_bcnt);
        int*             startsTbl  = (int*)(wsb + o_stbl);
        int*             bucketBase = (int*)(wsb + o_bbase);
        int*             bucketTot  = (int*)(wsb + o_btot);
        int*             rowptr     = (int*)(wsb + o_rowp);
        __half*          x16        = (__half*)(wsb + o_x16);
        __half*          h16        = (__half*)(wsb + o_h16);
        float*           h32        = out;   // layer-1 hidden lives in d_out

        const int n4 = N * FDIM / 4;
        convert_half4<<<(n4 + 255) / 256, 256, 0, stream>>>(
            (const float4*)x, (__half2*)x16, n4);

        // ---- Layer 1 ----
        p1_bin_stage<<<NBLK_G, 512, 0, stream>>>(e0, e0 + E, pairs1, blockcnt,
                                                 startsTbl, N, E, nb, chunk);
        p2a_colscan<<<nb, 64, 0, stream>>>(blockcnt, bucketTot, nb, NBLK_G);
        p2b_basescan<<<1, 512, 0, stream>>>(bucketTot, bucketBase, nb);
        p4_fine2<<<nb, 256, 0, stream>>>(pairs1, blockcnt, startsTbl, bucketBase,
                                         rowptr, csridx, N, E, nb, chunk, NBLK_G);
        fused_sage_kernel<true, false, true><<<FUSED_BLOCKS, 256, 0, stream>>>(
            rowptr, csridx, x16, x, W1, b1, R1, h32, h16, N);

        // ---- Layer 2 ----
        p1_bin_stage<<<NBLK_G, 512, 0, stream>>>(e1, e1 + E, pairs1, blockcnt,
                                                 startsTbl, N, E, nb, chunk);
        p2a_colscan<<<nb, 64, 0, stream>>>(blockcnt, bucketTot, nb, NBLK_G);
        p2b_basescan<<<1, 512, 0, stream>>>(bucketTot, bucketBase, nb);
        p4_fine2<<<nb, 256, 0, stream>>>(pairs1, blockcnt, startsTbl, bucketBase,
                                         rowptr, csridx, N, E, nb, chunk, NBLK_G);
        // in-place over d_out: gather reads h16, each thread reads only its
        // own h32 row before overwriting it
        fused_sage_kernel<false, true, false><<<FUSED_BLOCKS, 256, 0, stream>>>(
            rowptr, csridx, h16, h32, W2, b2, R2, out, (__half*)nullptr, N);
    } else {
        // Fallback: atomic scatter path (round-3, verified)
        float* agg = (float*)d_ws;
        float* deg = agg + (long long)N * FDIM;
        float* h = out;
        const long long total = (long long)E * FDIM;
        const int sblocks = (int)((total + 255) / 256);
        const int dblocks = (N + 3) / 4;

        hipMemsetAsync(agg, 0, ((size_t)N * FDIM + N) * sizeof(float), stream);
        scatter_kernel<<<sblocks, 256, 0, stream>>>(x, e0, e0 + E, agg, deg, N, total);
        dense_kernel<true, false><<<dblocks, 256, 0, stream>>>(agg, deg, x, W1, b1, R1, h, N);

        hipMemsetAsync(agg, 0, ((size_t)N * FDIM + N) * sizeof(float), stream);
        scatter_kernel<<<sblocks, 256, 0, stream>>>(h, e1, e1 + E, agg, deg, N, total);
        dense_kernel<false, true><<<dblocks, 256, 0, stream>>>(agg, deg, h, W2, b2, R2, out, N);
    }
}

// Round 15
// 311.578 us; speedup vs baseline: 1.3750x; 1.3750x over previous
//
#include <hip/hip_runtime.h>
#include <hip/hip_bf16.h>
#include <hip/hip_fp16.h>

#define FDIM 64
#define WPAD 68   // transposed-weight row stride (floats): 272 B, 16 B-aligned,
                  // bank=(4*lane+4k+i)%32 -> optimal 8 accesses/bank for b128

// Bucketed CSR build parameters
#define NBLK_G 256        // chunk-grid for p1
#define CHUNK_CAP 8192    // max edges per chunk block (32 KB LDS stage)
#define BKT_SHIFT 7
#define BKT_NODES 128     // dest nodes per bucket
#define NB_MAX 512        // max buckets (N <= 65536)
#define STCAP 8192        // P4 LDS stage cap (edges)

__device__ __forceinline__ int clampi(int v, int n) { return min(max(v, 0), n - 1); }

// --------------------- convert fp32 -> fp16 shadow table (x4) ---------------
__global__ __launch_bounds__(256) void convert_half4(
    const float4* __restrict__ in4, __half2* __restrict__ out2, int n4)
{
    int i = blockIdx.x * 256 + threadIdx.x;
    if (i >= n4) return;
    float4 v = in4[i];
    out2[2 * i]     = __floats2half2_rn(v.x, v.y);
    out2[2 * i + 1] = __floats2half2_rn(v.z, v.w);
}

// ---- P1 (single-pass): pack+stage+hist in ONE edge read; bin scatters
// directly to global (chunk-window-local, L2-absorbed). Saves 6.4 MB global
// read + one LDS pass per layer vs the r13 two-pass version. Output
// invariants identical: pairs1 chunk-grouped by bucket, blockcnt counts,
// startsTbl chunk-local exclusive starts.
__global__ __launch_bounds__(512) void p1_bin_stage(
    const int* __restrict__ rows, const int* __restrict__ cols,
    unsigned* __restrict__ pairs1, int* __restrict__ blockcnt,
    int* __restrict__ startsTbl, int n, int E, int nb, int chunk)
{
    __shared__ unsigned stage[CHUNK_CAP];
    __shared__ int hist[NB_MAX];
    __shared__ int curs[NB_MAX];
    int tid = threadIdx.x;
    int base = blockIdx.x * chunk;
    int cnt = E - base; if (cnt > chunk) cnt = chunk; if (cnt < 0) cnt = 0;
    for (int i = tid; i < NB_MAX; i += 512) hist[i] = 0;
    __syncthreads();
    // single global pass: pack + stage + histogram
    for (int i = tid; i < cnt; i += 512) {
        int c = clampi(cols[base + i], n);
        int r = clampi(rows[base + i], n);
        stage[i] = ((unsigned)r << 16) | (unsigned)c;
        atomicAdd(&hist[c >> BKT_SHIFT], 1);
    }
    __syncthreads();
    for (int b = tid; b < nb; b += 512) blockcnt[blockIdx.x * nb + b] = hist[b];
    __syncthreads();
    for (int off = 1; off < NB_MAX; off <<= 1) {
        int t = (tid >= off) ? hist[tid - off] : 0;
        __syncthreads();
        hist[tid] += t;
        __syncthreads();
    }
    curs[tid] = (tid == 0) ? 0 : hist[tid - 1];
    __syncthreads();
    // persist chunk-local exclusive starts BEFORE atomics mutate curs
    for (int b = tid; b < nb; b += 512) startsTbl[blockIdx.x * nb + b] = curs[b];
    __syncthreads();
    // bin: scatter directly to global within this chunk's 32 KB window
    for (int i = tid; i < cnt; i += 512) {
        unsigned pk = stage[i];
        int p = atomicAdd(&curs[(pk & 0xFFFFu) >> BKT_SHIFT], 1);
        pairs1[base + p] = pk;
    }
}

// --------------------- P2a: per-bucket column scan (1 wave / bucket) --------
__global__ __launch_bounds__(64) void p2a_colscan(
    int* __restrict__ blockcnt, int* __restrict__ bucketTot, int nb, int nblk)
{
    int b = blockIdx.x;
    int lane = threadIdx.x;
    int chunk = (nblk + 63) >> 6;
    int beg = lane * chunk;
    int endi = min(beg + chunk, nblk);
    int vals[8];
    int s = 0;
    for (int i = beg, j = 0; i < endi; ++i, ++j) {
        vals[j] = blockcnt[(size_t)i * nb + b];
        s += vals[j];
    }
    int incl = s;
#pragma unroll
    for (int o = 1; o < 64; o <<= 1) {
        int t = __shfl_up(incl, o, 64);
        if (lane >= o) incl += t;
    }
    int run = incl - s;
    for (int i = beg, j = 0; i < endi; ++i, ++j) {
        int t = vals[j];
        blockcnt[(size_t)i * nb + b] = run;
        run += t;
    }
    if (lane == 63) bucketTot[b] = incl;
}

// --------------------- P2b: bucket totals -> bucket bases -------------------
__global__ __launch_bounds__(512) void p2b_basescan(
    const int* __restrict__ bucketTot, int* __restrict__ bucketBase, int nb)
{
    __shared__ int tot[NB_MAX];
    int tid = threadIdx.x;
    tot[tid] = (tid < nb) ? bucketTot[tid] : 0;
    __syncthreads();
    for (int off = 1; off < NB_MAX; off <<= 1) {
        int t = (tid >= off) ? tot[tid - off] : 0;
        __syncthreads();
        tot[tid] += t;
        __syncthreads();
    }
    if (tid < nb) bucketBase[tid] = (tid == 0) ? 0 : tot[tid - 1];
    if (tid == 0) bucketBase[nb] = tot[nb - 1];
}

// ---- P4: per-bucket fine CSR, staging runs straight from pairs1 ------------
__global__ __launch_bounds__(256) void p4_fine2(
    const unsigned* __restrict__ pairs1, const int* __restrict__ blockcnt,
    const int* __restrict__ startsTbl, const int* __restrict__ bucketBase,
    int* __restrict__ rowptr, unsigned short* __restrict__ csridx,
    int n, int E, int nb, int chunk, int nblk)
{
    __shared__ unsigned st[STCAP];
    __shared__ int h[BKT_NODES];
    __shared__ int cur[BKT_NODES];
    int tid = threadIdx.x;
    int b = blockIdx.x;
    int beg = bucketBase[b], end = bucketBase[b + 1];
    int cnt = end - beg;
    for (int i = tid; i < BKT_NODES; i += 256) h[i] = 0;
    __syncthreads();
    bool fit = (cnt <= STCAP);     // block-uniform -> in-branch barriers legal
    if (fit) {
        for (int i = tid; i < nblk; i += 256) {
            int ccnt = E - i * chunk; if (ccnt > chunk) ccnt = chunk; if (ccnt < 0) ccnt = 0;
            int stt = startsTbl[(size_t)i * nb + b];
            int enn = (b + 1 < nb) ? startsTbl[(size_t)i * nb + b + 1] : ccnt;
            int dst = blockcnt[(size_t)i * nb + b];
            for (int j = stt; j < enn; ++j)
                st[dst + (j - stt)] = pairs1[(size_t)i * chunk + j];
        }
        __syncthreads();
        for (int i = tid; i < cnt; i += 256)
            atomicAdd(&h[st[i] & (BKT_NODES - 1)], 1);
    } else {
        for (int i = tid; i < nblk; i += 256) {
            int ccnt = E - i * chunk; if (ccnt > chunk) ccnt = chunk; if (ccnt < 0) ccnt = 0;
            int stt = startsTbl[(size_t)i * nb + b];
            int enn = (b + 1 < nb) ? startsTbl[(size_t)i * nb + b + 1] : ccnt;
            for (int j = stt; j < enn; ++j)
                atomicAdd(&h[pairs1[(size_t)i * chunk + j] & (BKT_NODES - 1)], 1);
        }
    }
    // barrier between histogram atomics and scan (round-9 race fix)
    __syncthreads();
    for (int off = 1; off < BKT_NODES; off <<= 1) {
        int t = (tid >= off && tid < BKT_NODES) ? h[tid - off] : 0;
        __syncthreads();
        if (tid < BKT_NODES) h[tid] += t;
        __syncthreads();
    }
    if (tid < BKT_NODES) {
        int node = b * BKT_NODES + tid;
        int startl = (tid == 0) ? 0 : h[tid - 1];
        cur[tid] = startl;
        if (node < n) rowptr[node] = beg + startl;
    }
    __syncthreads();
    if (fit) {
        for (int i = tid; i < cnt; i += 256) {
            unsigned pk = st[i];
            int p = atomicAdd(&cur[pk & (BKT_NODES - 1)], 1);
            csridx[beg + p] = (unsigned short)(pk >> 16);
        }
    } else {
        for (int i = tid; i < nblk; i += 256) {
            int ccnt = E - i * chunk; if (ccnt > chunk) ccnt = chunk; if (ccnt < 0) ccnt = 0;
            int stt = startsTbl[(size_t)i * nb + b];
            int enn = (b + 1 < nb) ? startsTbl[(size_t)i * nb + b + 1] : ccnt;
            for (int j = stt; j < enn; ++j) {
                unsigned pk = pairs1[(size_t)i * chunk + j];
                int p = atomicAdd(&cur[pk & (BKT_NODES - 1)], 1);
                csridx[beg + p] = (unsigned short)(pk >> 16);
            }
        }
    }
    if (b == nb - 1 && tid == 0) rowptr[n] = E;
}

// ------ Fused gather(mean, fp16 table) + dense — ROUND-13 VERBATIM ----------
// VGPR must stay <= 64 (HW wave-eligibility quantum: 8 waves/SIMD at <=64,
// halves above — r8/r10/r12/r14 all crossed it and regressed to ~20% occ).
// fp32 weights transposed+padded in LDS; b128 epilogue (64 LDS instr/node).
template <bool RELU, bool NORM, bool W16>
__global__ __launch_bounds__(256) void fused_sage_kernel(
    const int* __restrict__ rowptr, const unsigned short* __restrict__ csridx,
    const __half* __restrict__ src16, const float* __restrict__ src32,
    const float* __restrict__ W, const float* __restrict__ bvec,
    const float* __restrict__ R, float* __restrict__ out32,
    __half* __restrict__ out16, int n)
{
    __shared__ __align__(16) float Wt[FDIM][WPAD];   // Wt[j][k] = W[k][j]
    __shared__ __align__(16) float Rt[FDIM][WPAD];
    __shared__ float bs[FDIM];
    __shared__ __align__(16) float aRow[4][FDIM];
    __shared__ __align__(16) float xRow[4][FDIM];
    int tid = threadIdx.x;
    for (int i = tid; i < FDIM * FDIM; i += 256) {
        int k = i >> 6, j = i & 63;
        Wt[j][k] = W[i];           // W row-major [k][j]
        Rt[j][k] = R[i];
    }
    if (tid < FDIM) bs[tid] = bvec[tid];
    __syncthreads();

    int lane = tid & 63, w = tid >> 6;
    int g = lane >> 4;        // edge sub-group 0..3
    int q = lane & 15;        // 4-feature chunk within row

    for (int node = blockIdx.x * 4 + w; node < n; node += gridDim.x * 4) {
        int beg = rowptr[node], end = rowptr[node + 1];
        float4 s4 = make_float4(0.f, 0.f, 0.f, 0.f);
        for (int base = beg; base < end; base += 64) {
            int cnt = end - base; if (cnt > 64) cnt = 64;
            int ei = base + lane;
            int myidx = (ei < end) ? (int)csridx[ei] : 0;
            int steps = (cnt + 3) >> 2;
            for (int t = 0; t < steps; ++t) {
                int e = (t << 2) | g;
                int sidx = __shfl(myidx, e, 64);
                if (e < cnt) {
                    const float2* rp = (const float2*)(src16 + ((size_t)sidx << 6));
                    float2 vv = rp[q];                 // 4 halves = 8 B
                    __half2 ha = *reinterpret_cast<__half2*>(&vv.x);
                    __half2 hb = *reinterpret_cast<__half2*>(&vv.y);
                    float2 fa = __half22float2(ha);
                    float2 fb = __half22float2(hb);
                    s4.x += fa.x; s4.y += fa.y; s4.z += fb.x; s4.w += fb.y;
                }
            }
        }
#pragma unroll
        for (int o = 16; o < 64; o <<= 1) {
            s4.x += __shfl_xor(s4.x, o, 64);
            s4.y += __shfl_xor(s4.y, o, 64);
            s4.z += __shfl_xor(s4.z, o, 64);
            s4.w += __shfl_xor(s4.w, o, 64);
        }
        float dinv = 1.0f / fmaxf((float)(end - beg), 1.0f);
        if (g == 0) {
            aRow[w][q * 4 + 0] = s4.x * dinv;
            aRow[w][q * 4 + 1] = s4.y * dinv;
            aRow[w][q * 4 + 2] = s4.z * dinv;
            aRow[w][q * 4 + 3] = s4.w * dinv;
        }
        xRow[w][lane] = src32[((size_t)node << 6) + lane];
        // wave-local LDS RAW: ordered within the wave, no barrier needed
        float acc = bs[lane];
#pragma unroll
        for (int k4 = 0; k4 < FDIM / 4; ++k4) {
            float4 a4 = *(const float4*)&aRow[w][k4 * 4];   // broadcast b128
            float4 x4 = *(const float4*)&xRow[w][k4 * 4];
            float4 w4 = *(const float4*)&Wt[lane][k4 * 4];  // b128, 8/bank
            float4 r4 = *(const float4*)&Rt[lane][k4 * 4];
            acc = fmaf(a4.x, w4.x, acc);
            acc = fmaf(a4.y, w4.y, acc);
            acc = fmaf(a4.z, w4.z, acc);
            acc = fmaf(a4.w, w4.w, acc);
            acc = fmaf(x4.x, r4.x, acc);
            acc = fmaf(x4.y, r4.y, acc);
            acc = fmaf(x4.z, r4.z, acc);
            acc = fmaf(x4.w, r4.w, acc);
        }
        if (RELU) acc = fmaxf(acc, 0.0f);
        if (NORM) {
            float ss = acc * acc;
#pragma unroll
            for (int o = 32; o; o >>= 1) ss += __shfl_xor(ss, o, 64);
            acc *= 1.0f / fmaxf(sqrtf(ss), 1e-12f);
        }
        out32[((size_t)node << 6) + lane] = acc;
        if (W16) out16[((size_t)node << 6) + lane] = __float2half(acc);
    }
}

// ----------------- Atomic scatter path (fallback, 13.0 MB ws) ---------------
__global__ __launch_bounds__(256) void scatter_kernel(
    const float* __restrict__ src, const int* __restrict__ rows, const int* __restrict__ cols,
    float* __restrict__ agg, float* __restrict__ deg, int n, long long total)
{
    long long gid = (long long)blockIdx.x * 256 + threadIdx.x;
    if (gid >= total) return;
    int e = (int)(gid >> 6);
    int f = (int)(gid & 63);
    int r = clampi(rows[e], n), c = clampi(cols[e], n);
    atomicAdd(&agg[(long long)c * FDIM + f], src[(long long)r * FDIM + f]);
    if (f == 0) atomicAdd(&deg[c], 1.0f);
}

template <bool RELU, bool NORM>
__global__ __launch_bounds__(256) void dense_kernel(
    const float* __restrict__ agg, const float* __restrict__ deg, const float* __restrict__ x,
    const float* __restrict__ W, const float* __restrict__ b,
    const float* __restrict__ R, float* __restrict__ out, int n)
{
    __shared__ float Ws[FDIM][FDIM];
    __shared__ float Rs[FDIM][FDIM];
    __shared__ float bs[FDIM];
    __shared__ float aRow[4][FDIM];
    __shared__ float xRow[4][FDIM];
    int tid = threadIdx.x;
    for (int i = tid; i < FDIM * FDIM; i += 256) {
        Ws[i >> 6][i & 63] = W[i];
        Rs[i >> 6][i & 63] = R[i];
    }
    if (tid < FDIM) bs[tid] = b[tid];
    int j = tid & 63, r = tid >> 6;
    int row = blockIdx.x * 4 + r;
    if (row < n) {
        float d = fmaxf(deg[row], 1.0f);
        aRow[r][j] = agg[(long long)row * FDIM + j] / d;
        xRow[r][j] = x[(long long)row * FDIM + j];
    }
    __syncthreads();
    if (row >= n) return;
    float acc = bs[j];
#pragma unroll
    for (int k = 0; k < FDIM; ++k)
        acc = fmaf(aRow[r][k], Ws[k][j], fmaf(xRow[r][k], Rs[k][j], acc));
    if (RELU) acc = fmaxf(acc, 0.0f);
    if (NORM) {
        float ss = acc * acc;
#pragma unroll
        for (int o = 32; o; o >>= 1) ss += __shfl_xor(ss, o, 64);
        acc *= 1.0f / fmaxf(sqrtf(ss), 1e-12f);
    }
    out[(long long)row * FDIM + j] = acc;
}

// ---------------------------------------------------------------------------
extern "C" void kernel_launch(void* const* d_in, const int* in_sizes, int n_in,
                              void* d_out, int out_size, void* d_ws, size_t ws_size,
                              hipStream_t stream)
{
    const float* x  = (const float*)d_in[0];
    const int*   e0 = (const int*)d_in[1];
    const int*   e1 = (const int*)d_in[2];
    const float* W1 = (const float*)d_in[3];
    const float* b1 = (const float*)d_in[4];
    const float* R1 = (const float*)d_in[5];
    const float* W2 = (const float*)d_in[6];
    const float* b2 = (const float*)d_in[7];
    const float* R2 = (const float*)d_in[8];
    float* out = (float*)d_out;

    const int N = in_sizes[0] / FDIM;     // 50000
    const int E = in_sizes[1] / 2;        // 1600000

    const int nb = (N + BKT_NODES - 1) >> BKT_SHIFT;
    const int chunk = (E + NBLK_G - 1) / NBLK_G;
    const int FUSED_BLOCKS = 1024;        // 4 blocks/CU at ~37 KB LDS

    // Workspace (16-B aligned): pairs1[E] u32 | csridx[E] u16 |
    // blockcnt[NBLK_G*nb] | startsTbl[NBLK_G*nb] | bucketBase[nb+1] |
    // bucketTot[nb] | rowptr[N+1] | x16[N*64] half | h16[N*64] half  (~24.4 MB)
    auto align16 = [](size_t v) { return (v + 15) & ~(size_t)15; };
    size_t off = 0;
    size_t o_pairs1 = off; off = align16(off + (size_t)E * 4);
    size_t o_csr16  = off; off = align16(off + (size_t)E * 2);
    size_t o_bcnt   = off; off = align16(off + (size_t)NBLK_G * nb * 4);
    size_t o_stbl   = off; off = align16(off + (size_t)NBLK_G * nb * 4);
    size_t o_bbase  = off; off = align16(off + (size_t)(nb + 1) * 4);
    size_t o_btot   = off; off = align16(off + (size_t)nb * 4);
    size_t o_rowp   = off; off = align16(off + (size_t)(N + 1) * 4);
    size_t o_x16    = off; off = align16(off + (size_t)N * FDIM * 2);
    size_t o_h16    = off; off = align16(off + (size_t)N * FDIM * 2);
    const size_t need1 = off;

    const bool ok1 = (ws_size >= need1) && (N <= 65536) &&
                     (chunk <= CHUNK_CAP) && (nb <= NB_MAX) &&
                     ((N * FDIM & 3) == 0);

    if (ok1) {
        char* wsb = (char*)d_ws;
        unsigned*        pairs1     = (unsigned*)(wsb + o_pairs1);
        unsigned short*  csridx     = (unsigned short*)(wsb + o_csr16);
        int*             blockcnt   = (int*)(wsb + o_bcnt);
        int*             startsTbl  = (int*)(wsb + o_stbl);
        int*             bucketBase = (int*)(wsb + o_bbase);
        int*             bucketTot  = (int*)(wsb + o_btot);
        int*             rowptr     = (int*)(wsb + o_rowp);
        __half*          x16        = (__half*)(wsb + o_x16);
        __half*          h16        = (__half*)(wsb + o_h16);
        float*           h32        = out;   // layer-1 hidden lives in d_out

        const int n4 = N * FDIM / 4;
        convert_half4<<<(n4 + 255) / 256, 256, 0, stream>>>(
            (const float4*)x, (__half2*)x16, n4);

        // ---- Layer 1 ----
        p1_bin_stage<<<NBLK_G, 512, 0, stream>>>(e0, e0 + E, pairs1, blockcnt,
                                                 startsTbl, N, E, nb, chunk);
        p2a_colscan<<<nb, 64, 0, stream>>>(blockcnt, bucketTot, nb, NBLK_G);
        p2b_basescan<<<1, 512, 0, stream>>>(bucketTot, bucketBase, nb);
        p4_fine2<<<nb, 256, 0, stream>>>(pairs1, blockcnt, startsTbl, bucketBase,
                                         rowptr, csridx, N, E, nb, chunk, NBLK_G);
        fused_sage_kernel<true, false, true><<<FUSED_BLOCKS, 256, 0, stream>>>(
            rowptr, csridx, x16, x, W1, b1, R1, h32, h16, N);

        // ---- Layer 2 ----
        p1_bin_stage<<<NBLK_G, 512, 0, stream>>>(e1, e1 + E, pairs1, blockcnt,
                                                 startsTbl, N, E, nb, chunk);
        p2a_colscan<<<nb, 64, 0, stream>>>(blockcnt, bucketTot, nb, NBLK_G);
        p2b_basescan<<<1, 512, 0, stream>>>(bucketTot, bucketBase, nb);
        p4_fine2<<<nb, 256, 0, stream>>>(pairs1, blockcnt, startsTbl, bucketBase,
                                         rowptr, csridx, N, E, nb, chunk, NBLK_G);
        // in-place over d_out: gather reads h16, each thread reads only its
        // own h32 row before overwriting it
        fused_sage_kernel<false, true, false><<<FUSED_BLOCKS, 256, 0, stream>>>(
            rowptr, csridx, h16, h32, W2, b2, R2, out, (__half*)nullptr, N);
    } else {
        // Fallback: atomic scatter path (round-3, verified)
        float* agg = (float*)d_ws;
        float* deg = agg + (long long)N * FDIM;
        float* h = out;
        const long long total = (long long)E * FDIM;
        const int sblocks = (int)((total + 255) / 256);
        const int dblocks = (N + 3) / 4;

        hipMemsetAsync(agg, 0, ((size_t)N * FDIM + N) * sizeof(float), stream);
        scatter_kernel<<<sblocks, 256, 0, stream>>>(x, e0, e0 + E, agg, deg, N, total);
        dense_kernel<true, false><<<dblocks, 256, 0, stream>>>(agg, deg, x, W1, b1, R1, h, N);

        hipMemsetAsync(agg, 0, ((size_t)N * FDIM + N) * sizeof(float), stream);
        scatter_kernel<<<sblocks, 256, 0, stream>>>(h, e1, e1 + E, agg, deg, N, total);
        dense_kernel<false, true><<<dblocks, 256, 0, stream>>>(agg, deg, h, W2, b2, R2, out, N);
    }
}